// Round 13
// baseline (6692.354 us; speedup 1.0000x reference)
//
#include <hip/hip_runtime.h>
#include <math.h>

constexpr int SEQ   = 256;
constexpr int BATCH = 512;
constexpr int INDIM = 300;
constexpr int KIH   = 320;        // INDIM zero-padded to 5*64
constexpr int HDIM  = 512;
constexpr int LDIM  = 256;
constexpr int G4    = 4 * HDIM;   // 2048

typedef _Float16 f16x8 __attribute__((ext_vector_type(8)));
typedef _Float16 f16x4 __attribute__((ext_vector_type(4)));
typedef float    f32x4 __attribute__((ext_vector_type(4)));

// ===========================================================================
// FAST PATH kernels
// ===========================================================================

// slab[by][64 rows (g*16+r)][832 cols: 0..319 Wih(pad), 320..831 Whh], linear
__global__ __launch_bounds__(256) void prep_weights_kernel(
    const float* __restrict__ Wih, const float* __restrict__ Whh,
    const float* __restrict__ bih, const float* __restrict__ bhh,
    _Float16* __restrict__ slab, float* __restrict__ bsum)
{
    const int by = blockIdx.x >> 6;
    const int rl = blockIdx.x & 63;
    const int g  = rl >> 4, r = rl & 15;
    const int grow = g * HDIM + by * 16 + r;
    const int tid = threadIdx.x;
    if (tid < 208) {
        const int col0 = tid * 4;
        f16x4 v;
        #pragma unroll
        for (int e = 0; e < 4; ++e) {
            const int col = col0 + e;
            float f;
            if (col < KIH) f = (col < INDIM) ? Wih[(size_t)grow * INDIM + col] : 0.f;
            else           f = Whh[(size_t)grow * HDIM + (col - KIH)];
            v[e] = (_Float16)f;
        }
        *(f16x4*)(slab + ((size_t)(by * 64 + rl)) * 832 + col0) = v;
    } else if (tid == 208) {
        bsum[grow] = bih[grow] + bhh[grow];
    }
}

// xall[t][b][320] fp16, LINEAR (zero-padded 300->320)
__global__ __launch_bounds__(256) void prep_x_kernel(
    const float* __restrict__ x, _Float16* __restrict__ xall)
{
    const int rowl = threadIdx.x >> 6;
    const int s    = threadIdx.x & 63;
    const int row  = blockIdx.x * 4 + rowl;   // t*512 + b
    if (s >= 40) return;
    const int k0 = s * 8;
    const float* xr = x + (size_t)row * INDIM;
    f16x8 v;
    #pragma unroll
    for (int e = 0; e < 8; ++e)
        v[e] = (k0 + e < INDIM) ? (_Float16)xr[k0 + e] : (_Float16)0.f;
    *(f16x8*)(xall + (size_t)row * KIH + k0) = v;
}

// Persistent LSTM: 256 blocks x 512 threads (8 waves, 2/SIMD), 1 block/CU.
// Round-13 change vs round-11: WITHIN-XCD L2 COHERENCE instead of agent
// scope. Producer h/flag publishes are PLAIN stores (land in the XCD-local
// write-back L2; vmcnt(0) acks h before the flag issues). Consumers
// invalidate their own L1 (`buffer_inv`) after the flag is seen, then use
// PLAIN 16B loads -> the whole exchange runs at L2 latency instead of
// Infinity-Cache round trips (which is what agent-scope atomics cost on
// CDNA4, since per-XCD L2s are not cross-coherent). Validity of the
// same-bx==same-XCD mapping is evidenced by r6's 7x FETCH_SIZE drop from
// XCD-aligned grouping (plain x loads shared through one L2).
__global__ __launch_bounds__(512, 2) void lstm_persist13(
    const _Float16* __restrict__ xall,  // [SEQ+1][512][320] linear
    const _Float16* __restrict__ slab,  // [32][64][832] linear
    _Float16* __restrict__ hb,          // [2][512][512] linear ping-pong
    float* __restrict__ h32,            // [512][512] (written at t=SEQ-1)
    const float* __restrict__ bsum,     // [2048]
    int* __restrict__ cnt)              // flags[8][32]
{
    __shared__ _Float16 act[13][64][64];  // 106.5 KB, swizzled 128B rows
    __shared__ float    Gb2[2][64][68];   // 34.8 KB k-partial exchange

    const int tid  = threadIdx.x;
    const int wid  = tid >> 6;
    const int lane = tid & 63;
    const int gg   = wid >> 2;          // gate pair: rows gg*32..gg*32+31
    const int bh   = (wid >> 1) & 1;    // batch 32-half
    const int ks   = wid & 1;           // k 32-half within 64-chunk
    const int l15  = lane & 15;
    const int q4   = lane >> 4;
    const int bx   = blockIdx.x & 7;    // XCD-aligned group
    const int by   = blockIdx.x >> 3;   // 0..31
    const int b0   = bx * 64;
    const int hc0  = by * 16;

    // ---- weights -> registers via ATOMIC loads (remat-proof; one-time) ----
    f16x8 ws[13][2];
    {
        const _Float16* sb = slab + (size_t)by * 64 * 832
                                  + (size_t)(gg * 32 + l15) * 832 + ks * 32 + q4 * 8;
        #pragma unroll
        for (int ch = 0; ch < 13; ++ch)
            #pragma unroll
            for (int mt = 0; mt < 2; ++mt) {
                const unsigned long long* p = (const unsigned long long*)
                    (sb + (size_t)mt * 16 * 832 + ch * 64);
                union { unsigned long long u[2]; f16x8 v; } w;
                w.u[0] = __hip_atomic_load(p,     __ATOMIC_RELAXED,
                                           __HIP_MEMORY_SCOPE_AGENT);
                w.u[1] = __hip_atomic_load(p + 1, __ATOMIC_RELAXED,
                                           __HIP_MEMORY_SCOPE_AGENT);
                ws[ch][mt] = w.v;
            }
    }

    // ---- staging constants: thread (srow,suu) stages one 16B unit/slot ----
    const int srow  = tid >> 3;
    const int suu   = tid & 7;
    const int wbyte = srow * 128 + ((suu ^ (srow & 7)) << 4);  // swizzled

    // ---- B-frag read byte offsets (swizzled) ----
    int rbyte[2];
    #pragma unroll
    for (int bt = 0; bt < 2; ++bt) {
        const int row  = bh * 32 + bt * 16 + l15;
        const int unit = ks * 4 + q4;
        rbyte[bt] = row * 128 + ((unit ^ (row & 7)) << 4);
    }

    // ---- cell constants: 2 cells per thread ----
    const int bl  = tid >> 3;
    const int j0l = (tid & 7) * 2;
    const int bg  = b0 + bl;
    const int jg  = hc0 + j0l;
    float bsv[4][2];
    #pragma unroll
    for (int g = 0; g < 4; ++g) {
        bsv[g][0] = bsum[g * HDIM + jg];
        bsv[g][1] = bsum[g * HDIM + jg + 1];
    }
    float cv0 = 0.f, cv1 = 0.f;

#define BARX() do { asm volatile("" ::: "memory");                           \
                    __builtin_amdgcn_s_barrier();                            \
                    asm volatile("" ::: "memory"); } while (0)
#define LGKM0() asm volatile("s_waitcnt lgkmcnt(0)" ::: "memory")
#define VM0()   asm volatile("s_waitcnt vmcnt(0)" ::: "memory")
#define L1INV() asm volatile("buffer_inv" ::: "memory")

#define MFMA_CHUNK(CH) do {                                                  \
        const char* base = (const char*)&act[CH][0][0];                      \
        const f16x8 bf0 = *(const f16x8*)(base + rbyte[0]);                  \
        const f16x8 bf1 = *(const f16x8*)(base + rbyte[1]);                  \
        acc00 = __builtin_amdgcn_mfma_f32_16x16x32_f16(ws[CH][0], bf0, acc00, 0, 0, 0); \
        acc01 = __builtin_amdgcn_mfma_f32_16x16x32_f16(ws[CH][0], bf1, acc01, 0, 0, 0); \
        acc10 = __builtin_amdgcn_mfma_f32_16x16x32_f16(ws[CH][1], bf0, acc10, 0, 0, 0); \
        acc11 = __builtin_amdgcn_mfma_f32_16x16x32_f16(ws[CH][1], bf1, acc11, 0, 0, 0); \
    } while (0)

    // per-thread global bases
    const _Float16* xpt = xall + (size_t)(b0 + srow) * KIH + suu * 8;
    const _Float16* hpt = hb + (size_t)(b0 + srow) * HDIM + suu * 8;

    // ---- preload x for t=0 ----
    f16x8 xcur[5], xnxt[5];
    #pragma unroll
    for (int ch = 0; ch < 5; ++ch)
        xcur[ch] = *(const f16x8*)(xpt + ch * 64);

    for (int t = 0; t < SEQ; ++t) {
        // ---- stage x ----
        #pragma unroll
        for (int ch = 0; ch < 5; ++ch)
            *(f16x8*)((char*)&act[ch][0][0] + wbyte) = xcur[ch];
        LGKM0(); BARX();   // [1] x staged

        f32x4 acc00 = {0.f,0.f,0.f,0.f}, acc01 = {0.f,0.f,0.f,0.f};
        f32x4 acc10 = {0.f,0.f,0.f,0.f}, acc11 = {0.f,0.f,0.f,0.f};

        // ---- wave 0 polls (L1-inv + plain volatile load, L2-latency);
        //      waves 1-7 do x-chunk MFMAs meanwhile ----
        if (wid == 0) {
            if (t > 0) {
                const int* fp = cnt + bx * 32 + (lane & 31);
                int wd = 0;
                for (;;) {
                    int f;
                    L1INV();
                    asm volatile("global_load_dword %0, %1, off\n\t"
                                 "s_waitcnt vmcnt(0)"
                                 : "=v"(f) : "v"(fp) : "memory");
                    if (__all(f >= t)) break;
                    if (++wd > (1 << 14)) break;   // fast-fail watchdog
                    __builtin_amdgcn_s_sleep(1);
                }
                asm volatile("" ::: "memory");
            }
        } else {
            MFMA_CHUNK(0); MFMA_CHUNK(1); MFMA_CHUNK(2);
            MFMA_CHUNK(3); MFMA_CHUNK(4);
        }
        BARX();            // [2] h[t] ready (poll done)

        // ---- invalidate own L1, then PLAIN 16B h loads (local L2 hits) ----
        L1INV();
        f16x8 hr[8];
        {
            const _Float16* hbase = hpt + (size_t)(t & 1) * BATCH * HDIM;
            #pragma unroll
            for (int j = 0; j < 8; ++j)
                hr[j] = *(const f16x8*)(hbase + j * 64);
        }
        if (wid == 0) {
            MFMA_CHUNK(0); MFMA_CHUNK(1); MFMA_CHUNK(2);
            MFMA_CHUNK(3); MFMA_CHUNK(4);
        }
        // ---- prefetch x for step t+1 (padded row at t=SEQ-1) ----
        {
            const _Float16* xnb = xpt + (size_t)(t + 1) * BATCH * KIH;
            #pragma unroll
            for (int ch = 0; ch < 5; ++ch)
                xnxt[ch] = *(const f16x8*)(xnb + ch * 64);
        }
        // ---- stage h (compiler inserts vmcnt waits on hr deps) ----
        #pragma unroll
        for (int j = 0; j < 8; ++j)
            *(f16x8*)((char*)&act[5 + j][0][0] + wbyte) = hr[j];
        LGKM0(); BARX();   // [3] h staged

        // ---- MFMA h chunks ----
        MFMA_CHUNK(5); MFMA_CHUNK(6); MFMA_CHUNK(7); MFMA_CHUNK(8);
        MFMA_CHUNK(9); MFMA_CHUNK(10); MFMA_CHUNK(11); MFMA_CHUNK(12);

        // ---- gate k-partials -> Gb2 (disjoint per wave) ----
        #pragma unroll
        for (int q = 0; q < 4; ++q) {
            Gb2[ks][gg * 32 +      q4 * 4 + q][bh * 32 +      l15] = acc00[q];
            Gb2[ks][gg * 32 +      q4 * 4 + q][bh * 32 + 16 + l15] = acc01[q];
            Gb2[ks][gg * 32 + 16 + q4 * 4 + q][bh * 32 +      l15] = acc10[q];
            Gb2[ks][gg * 32 + 16 + q4 * 4 + q][bh * 32 + 16 + l15] = acc11[q];
        }
        LGKM0(); BARX();   // [4] gates complete

        // ---- LSTM cell: reduce ks halves, 2 cells/thread, publish ----
        {
            float pre[4][2];
            #pragma unroll
            for (int g = 0; g < 4; ++g) {
                pre[g][0] = Gb2[0][g * 16 + j0l    ][bl]
                          + Gb2[1][g * 16 + j0l    ][bl] + bsv[g][0];
                pre[g][1] = Gb2[0][g * 16 + j0l + 1][bl]
                          + Gb2[1][g * 16 + j0l + 1][bl] + bsv[g][1];
            }
            float hv0, hv1;
            {
                float vi = 1.f / (1.f + __expf(-pre[0][0]));
                float vf = 1.f / (1.f + __expf(-pre[1][0]));
                float vg = 1.f - 2.f / (__expf(2.f * pre[2][0]) + 1.f);
                float vo = 1.f / (1.f + __expf(-pre[3][0]));
                const float cc = vf * cv0 + vi * vg;
                cv0 = cc;
                hv0 = vo * (1.f - 2.f / (__expf(2.f * cc) + 1.f));
            }
            {
                float vi = 1.f / (1.f + __expf(-pre[0][1]));
                float vf = 1.f / (1.f + __expf(-pre[1][1]));
                float vg = 1.f - 2.f / (__expf(2.f * pre[2][1]) + 1.f);
                float vo = 1.f / (1.f + __expf(-pre[3][1]));
                const float cc = vf * cv1 + vi * vg;
                cv1 = cc;
                hv1 = vo * (1.f - 2.f / (__expf(2.f * cc) + 1.f));
            }
            union { unsigned int u; _Float16 v[2]; } hu;
            hu.v[0] = (_Float16)hv0; hu.v[1] = (_Float16)hv1;
            _Float16* hbw = hb + (size_t)((t + 1) & 1) * BATCH * HDIM;
            *(unsigned int*)(hbw + (size_t)bg * HDIM + jg) = hu.u;  // PLAIN
            if (t == SEQ - 1) {
                float* hp = h32 + (size_t)bg * HDIM + jg;
                hp[0] = hv0; hp[1] = hv1;
            }
        }
        VM0(); BARX();     // [5] h stores L2-acked (also drains xnxt loads)
        if (tid == 0) {
            int tv = t + 1;
            int* fp2 = cnt + bx * 32 + by;
            asm volatile("global_store_dword %0, %1, off"
                         :: "v"(fp2), "v"(tv) : "memory");
        }

        #pragma unroll
        for (int ch = 0; ch < 5; ++ch) xcur[ch] = xnxt[ch];
    }
#undef BARX
#undef LGKM0
#undef VM0
#undef L1INV
#undef MFMA_CHUNK
}

// ===========================================================================
// FALLBACK PATH (round-2, known-good) kernels
// ===========================================================================
__global__ __launch_bounds__(256) void prep_kernel(
    const float* __restrict__ Wih, const float* __restrict__ Whh,
    const float* __restrict__ bih, const float* __restrict__ bhh,
    _Float16* __restrict__ Wihc, _Float16* __restrict__ Whhc,
    float* __restrict__ bsum)
{
    const int g = blockIdx.x;
    for (int col = threadIdx.x; col < KIH; col += 256)
        Wihc[(size_t)g * KIH + col] =
            (col < INDIM) ? (_Float16)Wih[(size_t)g * INDIM + col] : (_Float16)0.f;
    for (int col = threadIdx.x; col < HDIM; col += 256)
        Whhc[(size_t)g * HDIM + col] = (_Float16)Whh[(size_t)g * HDIM + col];
    if (threadIdx.x == 0) bsum[g] = bih[g] + bhh[g];
}

__global__ __launch_bounds__(256) void fused_step_kernel(
    const float* __restrict__ xt, const _Float16* __restrict__ Wihc,
    const _Float16* __restrict__ Whhc, const float* __restrict__ bsum,
    float* __restrict__ c, float* __restrict__ h)
{
    __shared__ _Float16 As[32][72];
    __shared__ _Float16 Bs[128][72];
    __shared__ float    Gb[4][32][36];

    const int tid = threadIdx.x;
    const int b0  = blockIdx.x * 32;
    const int hc0 = blockIdx.y * 32;
    const int wid  = tid >> 6;
    const int lane = tid & 63;

    f32x4 acc[2][2] = {};
    const int arow = tid >> 3;
    const int ac8  = (tid & 7) * 8;
    const int brr  = tid >> 1;
    const int bseg = (tid & 1) * 32;

    for (int phase = 0; phase < 2; ++phase) {
        const float* Asrc = phase ? h : xt;
        const _Float16* Bsrc = phase ? Whhc : Wihc;
        const int Kpad = phase ? HDIM : KIH;
        const int Kval = phase ? HDIM : INDIM;
        const int astr = phase ? HDIM : INDIM;

        for (int k0 = 0; k0 < Kpad; k0 += 64) {
            const int gk = k0 + ac8;
            const float* pa = Asrc + (size_t)(b0 + arow) * astr + gk;
            float4 u = {0.f,0.f,0.f,0.f}, v = {0.f,0.f,0.f,0.f};
            if (gk + 3 < Kval)  u = *(const float4*)pa;
            if (gk + 7 < Kval)  v = *(const float4*)(pa + 4);
            f16x8 a8;
            a8[0]=(_Float16)u.x; a8[1]=(_Float16)u.y; a8[2]=(_Float16)u.z; a8[3]=(_Float16)u.w;
            a8[4]=(_Float16)v.x; a8[5]=(_Float16)v.y; a8[6]=(_Float16)v.z; a8[7]=(_Float16)v.w;
            const int grow = (brr >> 5) * HDIM + hc0 + (brr & 31);
            const _Float16* pb = Bsrc + (size_t)grow * Kpad + k0 + bseg;
            f16x8 w0 = *(const f16x8*)(pb + 0);
            f16x8 w1 = *(const f16x8*)(pb + 8);
            f16x8 w2 = *(const f16x8*)(pb + 16);
            f16x8 w3 = *(const f16x8*)(pb + 24);
            __syncthreads();
            *(f16x8*)&As[arow][ac8] = a8;
            *(f16x8*)&Bs[brr][bseg + 0]  = w0;
            *(f16x8*)&Bs[brr][bseg + 8]  = w1;
            *(f16x8*)&Bs[brr][bseg + 16] = w2;
            *(f16x8*)&Bs[brr][bseg + 24] = w3;
            __syncthreads();
            const int lr = lane & 15;
            const int lk = (lane >> 4) * 8;
            #pragma unroll
            for (int kf = 0; kf < 2; ++kf) {
                const int kl = kf * 32 + lk;
                f16x8 a0 = *(const f16x8*)&As[lr][kl];
                f16x8 a1 = *(const f16x8*)&As[16 + lr][kl];
                f16x8 bb0 = *(const f16x8*)&Bs[wid * 32 + lr][kl];
                f16x8 bb1 = *(const f16x8*)&Bs[wid * 32 + 16 + lr][kl];
                acc[0][0] = __builtin_amdgcn_mfma_f32_16x16x32_f16(a0, bb0, acc[0][0], 0, 0, 0);
                acc[0][1] = __builtin_amdgcn_mfma_f32_16x16x32_f16(a0, bb1, acc[0][1], 0, 0, 0);
                acc[1][0] = __builtin_amdgcn_mfma_f32_16x16x32_f16(a1, bb0, acc[1][0], 0, 0, 0);
                acc[1][1] = __builtin_amdgcn_mfma_f32_16x16x32_f16(a1, bb1, acc[1][1], 0, 0, 0);
            }
        }
    }
    __syncthreads();
    {
        const int cn = lane & 15;
        const int rbq = (lane >> 4) * 4;
        #pragma unroll
        for (int mi = 0; mi < 2; ++mi)
            #pragma unroll
            for (int ni = 0; ni < 2; ++ni)
                #pragma unroll
                for (int r = 0; r < 4; ++r)
                    Gb[wid][mi * 16 + rbq + r][ni * 16 + cn] = acc[mi][ni][r];
    }
    __syncthreads();
    {
        const int bl  = tid >> 3;
        const int jl0 = (tid & 7) * 4;
        const int gb  = b0 + bl;
        const int gj  = hc0 + jl0;
        const f32x4 ig = *(const f32x4*)&Gb[0][bl][jl0];
        const f32x4 fg = *(const f32x4*)&Gb[1][bl][jl0];
        const f32x4 gg = *(const f32x4*)&Gb[2][bl][jl0];
        const f32x4 og = *(const f32x4*)&Gb[3][bl][jl0];
        const f32x4 bi = *(const f32x4*)&bsum[0 * HDIM + gj];
        const f32x4 bf = *(const f32x4*)&bsum[1 * HDIM + gj];
        const f32x4 bg = *(const f32x4*)&bsum[2 * HDIM + gj];
        const f32x4 bo = *(const f32x4*)&bsum[3 * HDIM + gj];
        float* cp = c + (size_t)gb * HDIM + gj;
        float* hp = h + (size_t)gb * HDIM + gj;
        f32x4 cvv = *(const f32x4*)cp;
        f32x4 hv;
        #pragma unroll
        for (int q = 0; q < 4; ++q) {
            const float iv = 1.f / (1.f + __expf(-(ig[q] + bi[q])));
            const float fv = 1.f / (1.f + __expf(-(fg[q] + bf[q])));
            const float gv = tanhf(gg[q] + bg[q]);
            const float ov = 1.f / (1.f + __expf(-(og[q] + bo[q])));
            const float cc = fv * cvv[q] + iv * gv;
            cvv[q] = cc;
            hv[q] = ov * tanhf(cc);
        }
        *(f32x4*)cp = cvv;
        *(f32x4*)hp = hv;
    }
}

// ===========================================================================
// Shared epilogue
// ===========================================================================
__global__ __launch_bounds__(256) void bn_stats_kernel(
    const float* __restrict__ X, int nfeat,
    const float* __restrict__ gamma, const float* __restrict__ beta,
    float* __restrict__ s, float* __restrict__ t)
{
    const int f = blockIdx.x * 256 + threadIdx.x;
    if (f >= nfeat) return;
    float sum = 0.f, sq = 0.f;
    for (int b = 0; b < BATCH; ++b) {
        const float v = X[(size_t)b * nfeat + f];
        sum += v; sq += v * v;
    }
    const float mean = sum * (1.f / BATCH);
    const float var  = sq * (1.f / BATCH) - mean * mean;
    const float rstd = rsqrtf(var + 1e-5f);
    const float sc   = gamma[f] * rstd;
    s[f] = sc;
    t[f] = beta[f] - mean * sc;
}

__global__ __launch_bounds__(256) void fc1_kernel(
    const float* __restrict__ h, const float* __restrict__ s1,
    const float* __restrict__ t1, const float* __restrict__ W1,
    const float* __restrict__ b1, float* __restrict__ out1)
{
    const int b = blockIdx.x;
    const int l = threadIdx.x;
    const float* hbp = h  + (size_t)b * HDIM;
    const float* wl  = W1 + (size_t)l * HDIM;
    float acc = 0.f;
    for (int k = 0; k < HDIM; ++k)
        acc += (hbp[k] * s1[k] + t1[k]) * wl[k];
    out1[(size_t)b * LDIM + l] = acc + b1[l];
}

__global__ __launch_bounds__(256) void final_kernel(
    const float* __restrict__ out1, const float* __restrict__ s2,
    const float* __restrict__ t2, const float* __restrict__ W2,
    const float* __restrict__ b2, float* __restrict__ out)
{
    const int b = blockIdx.x;
    float v = out1[(size_t)b * LDIM + threadIdx.x];
    v = v * s2[threadIdx.x] + t2[threadIdx.x];
    v = fmaxf(v, 0.f);
    v *= W2[threadIdx.x];
    #pragma unroll
    for (int off = 32; off > 0; off >>= 1) v += __shfl_down(v, off);
    __shared__ float red[4];
    if ((threadIdx.x & 63) == 0) red[threadIdx.x >> 6] = v;
    __syncthreads();
    if (threadIdx.x == 0) {
        const float ssum = red[0] + red[1] + red[2] + red[3] + b2[0];
        out[b] = 4.f / (1.f + expf(-ssum));
    }
}

// ===========================================================================
extern "C" void kernel_launch(void* const* d_in, const int* in_sizes, int n_in,
                              void* d_out, int out_size, void* d_ws, size_t ws_size,
                              hipStream_t stream) {
    const float* x   = (const float*)d_in[0];
    const float* Wih = (const float*)d_in[1];
    const float* Whh = (const float*)d_in[2];
    const float* bih = (const float*)d_in[3];
    const float* bhh = (const float*)d_in[4];
    const float* g1  = (const float*)d_in[5];
    const float* be1 = (const float*)d_in[6];
    const float* W1  = (const float*)d_in[7];
    const float* b1  = (const float*)d_in[8];
    const float* g2  = (const float*)d_in[9];
    const float* be2 = (const float*)d_in[10];
    const float* W2  = (const float*)d_in[11];
    const float* b2  = (const float*)d_in[12];
    float* out = (float*)d_out;

    // ---- fast-path workspace layout ----
    const size_t SZ_XALL = (size_t)(SEQ + 1) * BATCH * KIH * 2;
    const size_t SZ_SLAB = (size_t)32 * 64 * 832 * 2;
    const size_t SZ_HB   = (size_t)2 * BATCH * HDIM * 2;
    const size_t SZ_H32  = (size_t)BATCH * HDIM * 4;
    const size_t SZ_BSUM = (size_t)G4 * 4;
    const size_t SZ_CNT  = (size_t)SEQ * 8 * 4;
    const size_t SZ_ST   = (size_t)(HDIM * 2 + LDIM * 2) * 4;
    const size_t SZ_OUT1 = (size_t)BATCH * LDIM * 4;
    const size_t NEED = SZ_XALL + SZ_SLAB + SZ_HB + SZ_H32 + SZ_BSUM +
                        SZ_CNT + SZ_ST + SZ_OUT1;

    if (ws_size >= NEED) {
        char* p = (char*)d_ws;
        _Float16* xall = (_Float16*)p;           p += SZ_XALL;
        _Float16* slab = (_Float16*)p;           p += SZ_SLAB;
        _Float16* hbuf = (_Float16*)p;           p += SZ_HB;
        float* h32     = (float*)p;              p += SZ_H32;
        float* bsum    = (float*)p;              p += SZ_BSUM;
        int*   cnt     = (int*)p;                p += SZ_CNT;
        float* s1 = (float*)p;                   p += HDIM * 4;
        float* t1 = (float*)p;                   p += HDIM * 4;
        float* s2 = (float*)p;                   p += LDIM * 4;
        float* t2 = (float*)p;                   p += LDIM * 4;
        float* out1 = (float*)p;

        hipMemsetAsync(hbuf, 0, SZ_HB, stream);
        hipMemsetAsync(cnt, 0, SZ_CNT, stream);
        prep_weights_kernel<<<2048, 256, 0, stream>>>(Wih, Whh, bih, bhh, slab, bsum);
        prep_x_kernel<<<SEQ * 128, 256, 0, stream>>>(x, xall);

        lstm_persist13<<<dim3(256), dim3(512), 0, stream>>>(
            xall, slab, hbuf, h32, bsum, cnt);

        bn_stats_kernel<<<2, 256, 0, stream>>>(h32, HDIM, g1, be1, s1, t1);
        fc1_kernel<<<BATCH, 256, 0, stream>>>(h32, s1, t1, W1, b1, out1);
        bn_stats_kernel<<<1, 256, 0, stream>>>(out1, LDIM, g2, be2, s2, t2);
        final_kernel<<<BATCH, 256, 0, stream>>>(out1, s2, t2, W2, b2, out);
    } else {
        // ---- fallback: round-2 path ----
        float* ws   = (float*)d_ws;
        float* h    = ws;
        float* c    = h + BATCH * HDIM;
        float* bsum = c + BATCH * HDIM;
        float* s1   = bsum + G4;
        float* t1   = s1 + HDIM;
        float* s2   = t1 + HDIM;
        float* t2   = s2 + LDIM;
        float* out1 = t2 + LDIM;
        _Float16* Wihc = (_Float16*)(out1 + (size_t)BATCH * LDIM);
        _Float16* Whhc = Wihc + (size_t)G4 * KIH;

        hipMemsetAsync(h, 0, (size_t)2 * BATCH * HDIM * sizeof(float), stream);
        prep_kernel<<<G4, 256, 0, stream>>>(Wih, Whh, bih, bhh, Wihc, Whhc, bsum);
        const dim3 sgrid(BATCH / 32, HDIM / 32);
        for (int t = 0; t < SEQ; ++t) {
            fused_step_kernel<<<sgrid, 256, 0, stream>>>(
                x + (size_t)t * BATCH * INDIM, Wihc, Whhc, bsum, c, h);
        }
        bn_stats_kernel<<<2, 256, 0, stream>>>(h, HDIM, g1, be1, s1, t1);
        fc1_kernel<<<BATCH, 256, 0, stream>>>(h, s1, t1, W1, b1, out1);
        bn_stats_kernel<<<1, 256, 0, stream>>>(out1, LDIM, g2, be2, s2, t2);
        final_kernel<<<BATCH, 256, 0, stream>>>(out1, s2, t2, W2, b2, out);
    }
}

// Round 14
// 1280.469 us; speedup vs baseline: 5.2265x; 5.2265x over previous
//
#include <hip/hip_runtime.h>
#include <math.h>

constexpr int SEQ   = 256;
constexpr int BATCH = 512;
constexpr int INDIM = 300;
constexpr int KIH   = 320;        // INDIM zero-padded to 5*64
constexpr int HDIM  = 512;
constexpr int LDIM  = 256;
constexpr int G4    = 4 * HDIM;   // 2048

typedef _Float16 f16x8 __attribute__((ext_vector_type(8)));
typedef _Float16 f16x4 __attribute__((ext_vector_type(4)));
typedef float    f32x4 __attribute__((ext_vector_type(4)));

// ===========================================================================
// FAST PATH kernels
// ===========================================================================

// slab[by][64 rows (g*16+r)][832 cols: 0..319 Wih(pad), 320..831 Whh], linear
__global__ __launch_bounds__(256) void prep_weights_kernel(
    const float* __restrict__ Wih, const float* __restrict__ Whh,
    const float* __restrict__ bih, const float* __restrict__ bhh,
    _Float16* __restrict__ slab, float* __restrict__ bsum)
{
    const int by = blockIdx.x >> 6;
    const int rl = blockIdx.x & 63;
    const int g  = rl >> 4, r = rl & 15;
    const int grow = g * HDIM + by * 16 + r;
    const int tid = threadIdx.x;
    if (tid < 208) {
        const int col0 = tid * 4;
        f16x4 v;
        #pragma unroll
        for (int e = 0; e < 4; ++e) {
            const int col = col0 + e;
            float f;
            if (col < KIH) f = (col < INDIM) ? Wih[(size_t)grow * INDIM + col] : 0.f;
            else           f = Whh[(size_t)grow * HDIM + (col - KIH)];
            v[e] = (_Float16)f;
        }
        *(f16x4*)(slab + ((size_t)(by * 64 + rl)) * 832 + col0) = v;
    } else if (tid == 208) {
        bsum[grow] = bih[grow] + bhh[grow];
    }
}

// xall[t][b][320] fp16, LINEAR (zero-padded 300->320)
__global__ __launch_bounds__(256) void prep_x_kernel(
    const float* __restrict__ x, _Float16* __restrict__ xall)
{
    const int rowl = threadIdx.x >> 6;
    const int s    = threadIdx.x & 63;
    const int row  = blockIdx.x * 4 + rowl;   // t*512 + b
    if (s >= 40) return;
    const int k0 = s * 8;
    const float* xr = x + (size_t)row * INDIM;
    f16x8 v;
    #pragma unroll
    for (int e = 0; e < 8; ++e)
        v[e] = (k0 + e < INDIM) ? (_Float16)xr[k0 + e] : (_Float16)0.f;
    *(f16x8*)(xall + (size_t)row * KIH + k0) = v;
}

// Persistent LSTM: 256 blocks x 512 threads (8 waves, 2/SIMD), 1 block/CU.
// Best-measured configuration (round 11): agent-scope h/flag exchange;
// wave 0 polls the producer flags (reduced flag-line traffic) with
// s_sleep(2); waves 1-7 run their x-chunk MFMAs during the poll; wave 0
// runs its x-MFMAs during the h-load flight. LDS: act[13] swizzled slots
// (conflict-free), Gb2 k-partial exchange; weights VGPR/AGPR-resident via
// atomic loads (remat-proof). 5 barriers/step.
__global__ __launch_bounds__(512, 2) void lstm_persist11(
    const _Float16* __restrict__ xall,  // [SEQ+1][512][320] linear
    const _Float16* __restrict__ slab,  // [32][64][832] linear
    _Float16* __restrict__ hb,          // [2][512][512] linear ping-pong
    float* __restrict__ h32,            // [512][512] (written at t=SEQ-1)
    const float* __restrict__ bsum,     // [2048]
    int* __restrict__ cnt)              // flags[8][32]
{
    __shared__ _Float16 act[13][64][64];  // 106.5 KB, swizzled 128B rows
    __shared__ float    Gb2[2][64][68];   // 34.8 KB k-partial exchange

    const int tid  = threadIdx.x;
    const int wid  = tid >> 6;
    const int lane = tid & 63;
    const int gg   = wid >> 2;          // gate pair: rows gg*32..gg*32+31
    const int bh   = (wid >> 1) & 1;    // batch 32-half
    const int ks   = wid & 1;           // k 32-half within 64-chunk
    const int l15  = lane & 15;
    const int q4   = lane >> 4;
    const int bx   = blockIdx.x & 7;    // XCD-aligned group
    const int by   = blockIdx.x >> 3;   // 0..31
    const int b0   = bx * 64;
    const int hc0  = by * 16;

    // ---- weights -> registers via ATOMIC loads (remat-proof) ----
    f16x8 ws[13][2];
    {
        const _Float16* sb = slab + (size_t)by * 64 * 832
                                  + (size_t)(gg * 32 + l15) * 832 + ks * 32 + q4 * 8;
        #pragma unroll
        for (int ch = 0; ch < 13; ++ch)
            #pragma unroll
            for (int mt = 0; mt < 2; ++mt) {
                const unsigned long long* p = (const unsigned long long*)
                    (sb + (size_t)mt * 16 * 832 + ch * 64);
                union { unsigned long long u[2]; f16x8 v; } w;
                w.u[0] = __hip_atomic_load(p,     __ATOMIC_RELAXED,
                                           __HIP_MEMORY_SCOPE_AGENT);
                w.u[1] = __hip_atomic_load(p + 1, __ATOMIC_RELAXED,
                                           __HIP_MEMORY_SCOPE_AGENT);
                ws[ch][mt] = w.v;
            }
    }

    // ---- staging constants: thread (srow,suu) stages one 16B unit/slot ----
    const int srow  = tid >> 3;
    const int suu   = tid & 7;
    const int wbyte = srow * 128 + ((suu ^ (srow & 7)) << 4);  // swizzled

    // ---- B-frag read byte offsets (swizzled) ----
    int rbyte[2];
    #pragma unroll
    for (int bt = 0; bt < 2; ++bt) {
        const int row  = bh * 32 + bt * 16 + l15;
        const int unit = ks * 4 + q4;
        rbyte[bt] = row * 128 + ((unit ^ (row & 7)) << 4);
    }

    // ---- cell constants: 2 cells per thread ----
    const int bl  = tid >> 3;
    const int j0l = (tid & 7) * 2;
    const int bg  = b0 + bl;
    const int jg  = hc0 + j0l;
    float bsv[4][2];
    #pragma unroll
    for (int g = 0; g < 4; ++g) {
        bsv[g][0] = bsum[g * HDIM + jg];
        bsv[g][1] = bsum[g * HDIM + jg + 1];
    }
    float cv0 = 0.f, cv1 = 0.f;

#define BARX() do { asm volatile("" ::: "memory");                           \
                    __builtin_amdgcn_s_barrier();                            \
                    asm volatile("" ::: "memory"); } while (0)
#define LGKM0() asm volatile("s_waitcnt lgkmcnt(0)" ::: "memory")
#define VM0()   asm volatile("s_waitcnt vmcnt(0)" ::: "memory")

#define MFMA_CHUNK(CH) do {                                                  \
        const char* base = (const char*)&act[CH][0][0];                      \
        const f16x8 bf0 = *(const f16x8*)(base + rbyte[0]);                  \
        const f16x8 bf1 = *(const f16x8*)(base + rbyte[1]);                  \
        acc00 = __builtin_amdgcn_mfma_f32_16x16x32_f16(ws[CH][0], bf0, acc00, 0, 0, 0); \
        acc01 = __builtin_amdgcn_mfma_f32_16x16x32_f16(ws[CH][0], bf1, acc01, 0, 0, 0); \
        acc10 = __builtin_amdgcn_mfma_f32_16x16x32_f16(ws[CH][1], bf0, acc10, 0, 0, 0); \
        acc11 = __builtin_amdgcn_mfma_f32_16x16x32_f16(ws[CH][1], bf1, acc11, 0, 0, 0); \
    } while (0)

    // per-thread global bases
    const _Float16* xpt = xall + (size_t)(b0 + srow) * KIH + suu * 8;
    const _Float16* hpt = hb + (size_t)(b0 + srow) * HDIM + suu * 8;

    // ---- preload x for t=0 ----
    f16x8 xcur[5], xnxt[5];
    #pragma unroll
    for (int ch = 0; ch < 5; ++ch)
        xcur[ch] = *(const f16x8*)(xpt + ch * 64);

    for (int t = 0; t < SEQ; ++t) {
        // ---- stage x ----
        #pragma unroll
        for (int ch = 0; ch < 5; ++ch)
            *(f16x8*)((char*)&act[ch][0][0] + wbyte) = xcur[ch];
        LGKM0(); BARX();   // [1] x staged

        f32x4 acc00 = {0.f,0.f,0.f,0.f}, acc01 = {0.f,0.f,0.f,0.f};
        f32x4 acc10 = {0.f,0.f,0.f,0.f}, acc11 = {0.f,0.f,0.f,0.f};

        // ---- wave 0 polls; waves 1-7 do x-chunk MFMAs meanwhile ----
        if (wid == 0) {
            if (t > 0) {
                const int* fp = cnt + bx * 32 + (lane & 31);
                int wd = 0;
                for (;;) {
                    const int f = __hip_atomic_load(fp, __ATOMIC_RELAXED,
                                                    __HIP_MEMORY_SCOPE_AGENT);
                    if (__all(f >= t)) break;
                    if (++wd > (1 << 20)) break;
                    __builtin_amdgcn_s_sleep(2);
                }
                asm volatile("" ::: "memory");
            }
        } else {
            MFMA_CHUNK(0); MFMA_CHUNK(1); MFMA_CHUNK(2);
            MFMA_CHUNK(3); MFMA_CHUNK(4);
        }
        BARX();            // [2] h[t] ready (poll done)

        // ---- h loads (all waves); wave 0's x-MFMAs overlap the flight ----
        f16x8 hr[8];
        {
            const _Float16* hbase = hpt + (size_t)(t & 1) * BATCH * HDIM;
            #pragma unroll
            for (int j = 0; j < 8; ++j) {
                const unsigned long long* p = (const unsigned long long*)
                    (hbase + j * 64);
                union { unsigned long long u[2]; f16x8 v; } hv;
                hv.u[0] = __hip_atomic_load(p,     __ATOMIC_RELAXED,
                                            __HIP_MEMORY_SCOPE_AGENT);
                hv.u[1] = __hip_atomic_load(p + 1, __ATOMIC_RELAXED,
                                            __HIP_MEMORY_SCOPE_AGENT);
                hr[j] = hv.v;
            }
        }
        if (wid == 0) {
            MFMA_CHUNK(0); MFMA_CHUNK(1); MFMA_CHUNK(2);
            MFMA_CHUNK(3); MFMA_CHUNK(4);
        }
        // ---- prefetch x for step t+1 (padded row at t=SEQ-1) ----
        {
            const _Float16* xnb = xpt + (size_t)(t + 1) * BATCH * KIH;
            #pragma unroll
            for (int ch = 0; ch < 5; ++ch)
                xnxt[ch] = *(const f16x8*)(xnb + ch * 64);
        }
        // ---- stage h (compiler inserts vmcnt waits on hr deps) ----
        #pragma unroll
        for (int j = 0; j < 8; ++j)
            *(f16x8*)((char*)&act[5 + j][0][0] + wbyte) = hr[j];
        LGKM0(); BARX();   // [3] h staged

        // ---- MFMA h chunks ----
        MFMA_CHUNK(5); MFMA_CHUNK(6); MFMA_CHUNK(7); MFMA_CHUNK(8);
        MFMA_CHUNK(9); MFMA_CHUNK(10); MFMA_CHUNK(11); MFMA_CHUNK(12);

        // ---- gate k-partials -> Gb2 (disjoint per wave) ----
        #pragma unroll
        for (int q = 0; q < 4; ++q) {
            Gb2[ks][gg * 32 +      q4 * 4 + q][bh * 32 +      l15] = acc00[q];
            Gb2[ks][gg * 32 +      q4 * 4 + q][bh * 32 + 16 + l15] = acc01[q];
            Gb2[ks][gg * 32 + 16 + q4 * 4 + q][bh * 32 +      l15] = acc10[q];
            Gb2[ks][gg * 32 + 16 + q4 * 4 + q][bh * 32 + 16 + l15] = acc11[q];
        }
        LGKM0(); BARX();   // [4] gates complete

        // ---- LSTM cell: reduce ks halves, 2 cells/thread, publish ----
        {
            float pre[4][2];
            #pragma unroll
            for (int g = 0; g < 4; ++g) {
                pre[g][0] = Gb2[0][g * 16 + j0l    ][bl]
                          + Gb2[1][g * 16 + j0l    ][bl] + bsv[g][0];
                pre[g][1] = Gb2[0][g * 16 + j0l + 1][bl]
                          + Gb2[1][g * 16 + j0l + 1][bl] + bsv[g][1];
            }
            float hv0, hv1;
            {
                float vi = 1.f / (1.f + __expf(-pre[0][0]));
                float vf = 1.f / (1.f + __expf(-pre[1][0]));
                float vg = 1.f - 2.f / (__expf(2.f * pre[2][0]) + 1.f);
                float vo = 1.f / (1.f + __expf(-pre[3][0]));
                const float cc = vf * cv0 + vi * vg;
                cv0 = cc;
                hv0 = vo * (1.f - 2.f / (__expf(2.f * cc) + 1.f));
            }
            {
                float vi = 1.f / (1.f + __expf(-pre[0][1]));
                float vf = 1.f / (1.f + __expf(-pre[1][1]));
                float vg = 1.f - 2.f / (__expf(2.f * pre[2][1]) + 1.f);
                float vo = 1.f / (1.f + __expf(-pre[3][1]));
                const float cc = vf * cv1 + vi * vg;
                cv1 = cc;
                hv1 = vo * (1.f - 2.f / (__expf(2.f * cc) + 1.f));
            }
            union { unsigned int u; _Float16 v[2]; } hu;
            hu.v[0] = (_Float16)hv0; hu.v[1] = (_Float16)hv1;
            _Float16* hbw = hb + (size_t)((t + 1) & 1) * BATCH * HDIM;
            __hip_atomic_store((unsigned int*)(hbw + (size_t)bg * HDIM + jg),
                               hu.u, __ATOMIC_RELAXED, __HIP_MEMORY_SCOPE_AGENT);
            if (t == SEQ - 1) {
                float* hp = h32 + (size_t)bg * HDIM + jg;
                hp[0] = hv0; hp[1] = hv1;
            }
        }
        VM0(); BARX();     // [5] publish drained (also xnxt loads)
        if (tid == 0)
            __hip_atomic_store(&cnt[bx * 32 + by], t + 1, __ATOMIC_RELAXED,
                               __HIP_MEMORY_SCOPE_AGENT);

        #pragma unroll
        for (int ch = 0; ch < 5; ++ch) xcur[ch] = xnxt[ch];
    }
#undef BARX
#undef LGKM0
#undef VM0
#undef MFMA_CHUNK
}

// ===========================================================================
// FALLBACK PATH (round-2, known-good) kernels
// ===========================================================================
__global__ __launch_bounds__(256) void prep_kernel(
    const float* __restrict__ Wih, const float* __restrict__ Whh,
    const float* __restrict__ bih, const float* __restrict__ bhh,
    _Float16* __restrict__ Wihc, _Float16* __restrict__ Whhc,
    float* __restrict__ bsum)
{
    const int g = blockIdx.x;
    for (int col = threadIdx.x; col < KIH; col += 256)
        Wihc[(size_t)g * KIH + col] =
            (col < INDIM) ? (_Float16)Wih[(size_t)g * INDIM + col] : (_Float16)0.f;
    for (int col = threadIdx.x; col < HDIM; col += 256)
        Whhc[(size_t)g * HDIM + col] = (_Float16)Whh[(size_t)g * HDIM + col];
    if (threadIdx.x == 0) bsum[g] = bih[g] + bhh[g];
}

__global__ __launch_bounds__(256) void fused_step_kernel(
    const float* __restrict__ xt, const _Float16* __restrict__ Wihc,
    const _Float16* __restrict__ Whhc, const float* __restrict__ bsum,
    float* __restrict__ c, float* __restrict__ h)
{
    __shared__ _Float16 As[32][72];
    __shared__ _Float16 Bs[128][72];
    __shared__ float    Gb[4][32][36];

    const int tid = threadIdx.x;
    const int b0  = blockIdx.x * 32;
    const int hc0 = blockIdx.y * 32;
    const int wid  = tid >> 6;
    const int lane = tid & 63;

    f32x4 acc[2][2] = {};
    const int arow = tid >> 3;
    const int ac8  = (tid & 7) * 8;
    const int brr  = tid >> 1;
    const int bseg = (tid & 1) * 32;

    for (int phase = 0; phase < 2; ++phase) {
        const float* Asrc = phase ? h : xt;
        const _Float16* Bsrc = phase ? Whhc : Wihc;
        const int Kpad = phase ? HDIM : KIH;
        const int Kval = phase ? HDIM : INDIM;
        const int astr = phase ? HDIM : INDIM;

        for (int k0 = 0; k0 < Kpad; k0 += 64) {
            const int gk = k0 + ac8;
            const float* pa = Asrc + (size_t)(b0 + arow) * astr + gk;
            float4 u = {0.f,0.f,0.f,0.f}, v = {0.f,0.f,0.f,0.f};
            if (gk + 3 < Kval)  u = *(const float4*)pa;
            if (gk + 7 < Kval)  v = *(const float4*)(pa + 4);
            f16x8 a8;
            a8[0]=(_Float16)u.x; a8[1]=(_Float16)u.y; a8[2]=(_Float16)u.z; a8[3]=(_Float16)u.w;
            a8[4]=(_Float16)v.x; a8[5]=(_Float16)v.y; a8[6]=(_Float16)v.z; a8[7]=(_Float16)v.w;
            const int grow = (brr >> 5) * HDIM + hc0 + (brr & 31);
            const _Float16* pb = Bsrc + (size_t)grow * Kpad + k0 + bseg;
            f16x8 w0 = *(const f16x8*)(pb + 0);
            f16x8 w1 = *(const f16x8*)(pb + 8);
            f16x8 w2 = *(const f16x8*)(pb + 16);
            f16x8 w3 = *(const f16x8*)(pb + 24);
            __syncthreads();
            *(f16x8*)&As[arow][ac8] = a8;
            *(f16x8*)&Bs[brr][bseg + 0]  = w0;
            *(f16x8*)&Bs[brr][bseg + 8]  = w1;
            *(f16x8*)&Bs[brr][bseg + 16] = w2;
            *(f16x8*)&Bs[brr][bseg + 24] = w3;
            __syncthreads();
            const int lr = lane & 15;
            const int lk = (lane >> 4) * 8;
            #pragma unroll
            for (int kf = 0; kf < 2; ++kf) {
                const int kl = kf * 32 + lk;
                f16x8 a0 = *(const f16x8*)&As[lr][kl];
                f16x8 a1 = *(const f16x8*)&As[16 + lr][kl];
                f16x8 bb0 = *(const f16x8*)&Bs[wid * 32 + lr][kl];
                f16x8 bb1 = *(const f16x8*)&Bs[wid * 32 + 16 + lr][kl];
                acc[0][0] = __builtin_amdgcn_mfma_f32_16x16x32_f16(a0, bb0, acc[0][0], 0, 0, 0);
                acc[0][1] = __builtin_amdgcn_mfma_f32_16x16x32_f16(a0, bb1, acc[0][1], 0, 0, 0);
                acc[1][0] = __builtin_amdgcn_mfma_f32_16x16x32_f16(a1, bb0, acc[1][0], 0, 0, 0);
                acc[1][1] = __builtin_amdgcn_mfma_f32_16x16x32_f16(a1, bb1, acc[1][1], 0, 0, 0);
            }
        }
    }
    __syncthreads();
    {
        const int cn = lane & 15;
        const int rbq = (lane >> 4) * 4;
        #pragma unroll
        for (int mi = 0; mi < 2; ++mi)
            #pragma unroll
            for (int ni = 0; ni < 2; ++ni)
                #pragma unroll
                for (int r = 0; r < 4; ++r)
                    Gb[wid][mi * 16 + rbq + r][ni * 16 + cn] = acc[mi][ni][r];
    }
    __syncthreads();
    {
        const int bl  = tid >> 3;
        const int jl0 = (tid & 7) * 4;
        const int gb  = b0 + bl;
        const int gj  = hc0 + jl0;
        const f32x4 ig = *(const f32x4*)&Gb[0][bl][jl0];
        const f32x4 fg = *(const f32x4*)&Gb[1][bl][jl0];
        const f32x4 gg = *(const f32x4*)&Gb[2][bl][jl0];
        const f32x4 og = *(const f32x4*)&Gb[3][bl][jl0];
        const f32x4 bi = *(const f32x4*)&bsum[0 * HDIM + gj];
        const f32x4 bf = *(const f32x4*)&bsum[1 * HDIM + gj];
        const f32x4 bg = *(const f32x4*)&bsum[2 * HDIM + gj];
        const f32x4 bo = *(const f32x4*)&bsum[3 * HDIM + gj];
        float* cp = c + (size_t)gb * HDIM + gj;
        float* hp = h + (size_t)gb * HDIM + gj;
        f32x4 cvv = *(const f32x4*)cp;
        f32x4 hv;
        #pragma unroll
        for (int q = 0; q < 4; ++q) {
            const float iv = 1.f / (1.f + __expf(-(ig[q] + bi[q])));
            const float fv = 1.f / (1.f + __expf(-(fg[q] + bf[q])));
            const float gv = tanhf(gg[q] + bg[q]);
            const float ov = 1.f / (1.f + __expf(-(og[q] + bo[q])));
            const float cc = fv * cvv[q] + iv * gv;
            cvv[q] = cc;
            hv[q] = ov * tanhf(cc);
        }
        *(f32x4*)cp = cvv;
        *(f32x4*)hp = hv;
    }
}

// ===========================================================================
// Shared epilogue
// ===========================================================================
__global__ __launch_bounds__(256) void bn_stats_kernel(
    const float* __restrict__ X, int nfeat,
    const float* __restrict__ gamma, const float* __restrict__ beta,
    float* __restrict__ s, float* __restrict__ t)
{
    const int f = blockIdx.x * 256 + threadIdx.x;
    if (f >= nfeat) return;
    float sum = 0.f, sq = 0.f;
    for (int b = 0; b < BATCH; ++b) {
        const float v = X[(size_t)b * nfeat + f];
        sum += v; sq += v * v;
    }
    const float mean = sum * (1.f / BATCH);
    const float var  = sq * (1.f / BATCH) - mean * mean;
    const float rstd = rsqrtf(var + 1e-5f);
    const float sc   = gamma[f] * rstd;
    s[f] = sc;
    t[f] = beta[f] - mean * sc;
}

__global__ __launch_bounds__(256) void fc1_kernel(
    const float* __restrict__ h, const float* __restrict__ s1,
    const float* __restrict__ t1, const float* __restrict__ W1,
    const float* __restrict__ b1, float* __restrict__ out1)
{
    const int b = blockIdx.x;
    const int l = threadIdx.x;
    const float* hbp = h  + (size_t)b * HDIM;
    const float* wl  = W1 + (size_t)l * HDIM;
    float acc = 0.f;
    for (int k = 0; k < HDIM; ++k)
        acc += (hbp[k] * s1[k] + t1[k]) * wl[k];
    out1[(size_t)b * LDIM + l] = acc + b1[l];
}

__global__ __launch_bounds__(256) void final_kernel(
    const float* __restrict__ out1, const float* __restrict__ s2,
    const float* __restrict__ t2, const float* __restrict__ W2,
    const float* __restrict__ b2, float* __restrict__ out)
{
    const int b = blockIdx.x;
    float v = out1[(size_t)b * LDIM + threadIdx.x];
    v = v * s2[threadIdx.x] + t2[threadIdx.x];
    v = fmaxf(v, 0.f);
    v *= W2[threadIdx.x];
    #pragma unroll
    for (int off = 32; off > 0; off >>= 1) v += __shfl_down(v, off);
    __shared__ float red[4];
    if ((threadIdx.x & 63) == 0) red[threadIdx.x >> 6] = v;
    __syncthreads();
    if (threadIdx.x == 0) {
        const float ssum = red[0] + red[1] + red[2] + red[3] + b2[0];
        out[b] = 4.f / (1.f + expf(-ssum));
    }
}

// ===========================================================================
extern "C" void kernel_launch(void* const* d_in, const int* in_sizes, int n_in,
                              void* d_out, int out_size, void* d_ws, size_t ws_size,
                              hipStream_t stream) {
    const float* x   = (const float*)d_in[0];
    const float* Wih = (const float*)d_in[1];
    const float* Whh = (const float*)d_in[2];
    const float* bih = (const float*)d_in[3];
    const float* bhh = (const float*)d_in[4];
    const float* g1  = (const float*)d_in[5];
    const float* be1 = (const float*)d_in[6];
    const float* W1  = (const float*)d_in[7];
    const float* b1  = (const float*)d_in[8];
    const float* g2  = (const float*)d_in[9];
    const float* be2 = (const float*)d_in[10];
    const float* W2  = (const float*)d_in[11];
    const float* b2  = (const float*)d_in[12];
    float* out = (float*)d_out;

    // ---- fast-path workspace layout ----
    const size_t SZ_XALL = (size_t)(SEQ + 1) * BATCH * KIH * 2;
    const size_t SZ_SLAB = (size_t)32 * 64 * 832 * 2;
    const size_t SZ_HB   = (size_t)2 * BATCH * HDIM * 2;
    const size_t SZ_H32  = (size_t)BATCH * HDIM * 4;
    const size_t SZ_BSUM = (size_t)G4 * 4;
    const size_t SZ_CNT  = (size_t)SEQ * 8 * 4;
    const size_t SZ_ST   = (size_t)(HDIM * 2 + LDIM * 2) * 4;
    const size_t SZ_OUT1 = (size_t)BATCH * LDIM * 4;
    const size_t NEED = SZ_XALL + SZ_SLAB + SZ_HB + SZ_H32 + SZ_BSUM +
                        SZ_CNT + SZ_ST + SZ_OUT1;

    if (ws_size >= NEED) {
        char* p = (char*)d_ws;
        _Float16* xall = (_Float16*)p;           p += SZ_XALL;
        _Float16* slab = (_Float16*)p;           p += SZ_SLAB;
        _Float16* hbuf = (_Float16*)p;           p += SZ_HB;
        float* h32     = (float*)p;              p += SZ_H32;
        float* bsum    = (float*)p;              p += SZ_BSUM;
        int*   cnt     = (int*)p;                p += SZ_CNT;
        float* s1 = (float*)p;                   p += HDIM * 4;
        float* t1 = (float*)p;                   p += HDIM * 4;
        float* s2 = (float*)p;                   p += LDIM * 4;
        float* t2 = (float*)p;                   p += LDIM * 4;
        float* out1 = (float*)p;

        hipMemsetAsync(hbuf, 0, SZ_HB, stream);
        hipMemsetAsync(cnt, 0, SZ_CNT, stream);
        prep_weights_kernel<<<2048, 256, 0, stream>>>(Wih, Whh, bih, bhh, slab, bsum);
        prep_x_kernel<<<SEQ * 128, 256, 0, stream>>>(x, xall);

        lstm_persist11<<<dim3(256), dim3(512), 0, stream>>>(
            xall, slab, hbuf, h32, bsum, cnt);

        bn_stats_kernel<<<2, 256, 0, stream>>>(h32, HDIM, g1, be1, s1, t1);
        fc1_kernel<<<BATCH, 256, 0, stream>>>(h32, s1, t1, W1, b1, out1);
        bn_stats_kernel<<<1, 256, 0, stream>>>(out1, LDIM, g2, be2, s2, t2);
        final_kernel<<<BATCH, 256, 0, stream>>>(out1, s2, t2, W2, b2, out);
    } else {
        // ---- fallback: round-2 path ----
        float* ws   = (float*)d_ws;
        float* h    = ws;
        float* c    = h + BATCH * HDIM;
        float* bsum = c + BATCH * HDIM;
        float* s1   = bsum + G4;
        float* t1   = s1 + HDIM;
        float* s2   = t1 + HDIM;
        float* t2   = s2 + LDIM;
        float* out1 = t2 + LDIM;
        _Float16* Wihc = (_Float16*)(out1 + (size_t)BATCH * LDIM);
        _Float16* Whhc = Wihc + (size_t)G4 * KIH;

        hipMemsetAsync(h, 0, (size_t)2 * BATCH * HDIM * sizeof(float), stream);
        prep_kernel<<<G4, 256, 0, stream>>>(Wih, Whh, bih, bhh, Wihc, Whhc, bsum);
        const dim3 sgrid(BATCH / 32, HDIM / 32);
        for (int t = 0; t < SEQ; ++t) {
            fused_step_kernel<<<sgrid, 256, 0, stream>>>(
                x + (size_t)t * BATCH * INDIM, Wihc, Whhc, bsum, c, h);
        }
        bn_stats_kernel<<<2, 256, 0, stream>>>(h, HDIM, g1, be1, s1, t1);
        fc1_kernel<<<BATCH, 256, 0, stream>>>(h, s1, t1, W1, b1, out1);
        bn_stats_kernel<<<1, 256, 0, stream>>>(out1, LDIM, g2, be2, s2, t2);
        final_kernel<<<BATCH, 256, 0, stream>>>(out1, s2, t2, W2, b2, out);
    }
}